// Round 2
// baseline (1537.605 us; speedup 1.0000x reference)
//
#include <hip/hip_runtime.h>
#include <hip/hip_bf16.h>

// ---------------------------------------------------------------------------
// NNUE forward:
//   ft = [features1; features2] @ W_ft.T   (8192 x 257)
//   split-K bf16 MFMA with hi/lo error compensation (~fp32-accurate)
//   tail: bias+clamp, 512->32->32->1 MLP + 0.25 * psqtacc
// ---------------------------------------------------------------------------

#define K_DIM      41600     // FT_IN
#define N_REAL     257
#define N_PAD      272       // 17 * 16
#define ACC_STRIDE 272       // keeps rows 16B-aligned
#define B_ROWS     4096
#define M_TOTAL    8192
#define MT         128       // M rows per block
#define BK         32        // K per staging step
#define SPLITS     8
#define LDS_STRIDE 40        // 32 + 8 pad (16B-aligned rows, kills conflicts)

typedef __attribute__((ext_vector_type(8))) short  bf16x8;
typedef __attribute__((ext_vector_type(4))) short  bf16x4;
typedef __attribute__((ext_vector_type(4))) float  f32x4;

__device__ __forceinline__ short f2bf(float f) {
    __hip_bfloat16 h = __float2bfloat16(f);
    return __builtin_bit_cast(short, h);
}
__device__ __forceinline__ float bf2f(short s) {
    unsigned u = ((unsigned)(unsigned short)s) << 16;
    return __builtin_bit_cast(float, u);
}
// x ~= hi + lo, each bf16 (round-to-nearest): ~16-bit effective mantissa
__device__ __forceinline__ void cvt_hilo(const f32x4 v, bf16x4* hi, bf16x4* lo) {
    short h0 = f2bf(v.x), h1 = f2bf(v.y), h2 = f2bf(v.z), h3 = f2bf(v.w);
    *hi = (bf16x4){h0, h1, h2, h3};
    *lo = (bf16x4){ f2bf(v.x - bf2f(h0)), f2bf(v.y - bf2f(h1)),
                    f2bf(v.z - bf2f(h2)), f2bf(v.w - bf2f(h3)) };
}

// ---------------------------------------------------------------------------
// Kernel 1: split-K compensated-bf16 MFMA GEMM; atomicAdd into acc (8192x272)
// ---------------------------------------------------------------------------
__global__ __launch_bounds__(256, 2) void ft_gemm(
    const float* __restrict__ feat1, const float* __restrict__ feat2,
    const float* __restrict__ Wft, float* __restrict__ acc_ws)
{
    // 64,000 B static LDS (fits under 64 KB static cap; 2 blocks/CU = 128 KB)
    __shared__ __align__(16) short sAh[MT * LDS_STRIDE];     // 128 x 40
    __shared__ __align__(16) short sAl[MT * LDS_STRIDE];
    __shared__ __align__(16) short sWh[N_PAD * LDS_STRIDE];  // 272 x 40
    __shared__ __align__(16) short sWl[N_PAD * LDS_STRIDE];

    const int t    = threadIdx.x;
    const int wave = t >> 6;
    const int lane = t & 63;
    const int q    = lane >> 4;      // quad 0..3
    const int ml   = lane & 15;

    const int s     = blockIdx.x & 7;   // split id (aligns with XCD id)
    const int mtile = blockIdx.x >> 3;  // 0..63

    // 1300 k-steps = 8*162 + 4: first 4 splits take 163
    const int start  = s * 162 + (s < 4 ? s : 4);
    const int nsteps = 162 + (s < 4 ? 1 : 0);

    const float* Abase = (mtile < 32)
        ? (feat1 + (size_t)mtile * MT * K_DIM)
        : (feat2 + (size_t)(mtile - 32) * MT * K_DIM);

    f32x4 acc[2][17];
#pragma unroll
    for (int rt = 0; rt < 2; ++rt)
#pragma unroll
        for (int ct = 0; ct < 17; ++ct)
            acc[rt][ct] = (f32x4){0.f, 0.f, 0.f, 0.f};

    // LDS fragment element offsets
    const int aoff0 = (wave * 32 + ml) * LDS_STRIDE + q * 8;
    const int aoff1 = aoff0 + 16 * LDS_STRIDE;
    const int boffb = ml * LDS_STRIDE + q * 8;

    // per-thread staging geometry: chunk c = t + i*256 -> row c>>3, kq c&7
    const int srow = t >> 3;
    const int skq  = t & 7;

    f32x4 aV[4];   // A prefetch regs: rows srow + 32*i
    f32x4 wV[9];   // W prefetch regs: rows srow + 32*i (i=8 only t<128)

    auto load_step = [&](int step) {
        const int k0 = (start + step) * BK;
        const float* ap = Abase + (size_t)srow * K_DIM + k0 + skq * 4;
#pragma unroll
        for (int i = 0; i < 4; ++i)
            aV[i] = *reinterpret_cast<const f32x4*>(ap + (size_t)(32 * i) * K_DIM);
#pragma unroll
        for (int i = 0; i < 9; ++i) {
            const int row = srow + 32 * i;
            if (row < N_PAD) {
                const int grow = row < N_REAL ? row : (N_REAL - 1);
                wV[i] = *reinterpret_cast<const f32x4*>(
                    Wft + (size_t)grow * K_DIM + k0 + skq * 4);
            }
        }
    };

    load_step(0);

#pragma unroll 1
    for (int step = 0; step < nsteps; ++step) {
        __syncthreads();   // waves done reading LDS; also drains prefetch vmem

        // ---- convert + stage current slab (regs -> LDS)
#pragma unroll
        for (int i = 0; i < 4; ++i) {
            const int row = srow + 32 * i;
            bf16x4 h, l;
            cvt_hilo(aV[i], &h, &l);
            *reinterpret_cast<bf16x4*>(&sAh[row * LDS_STRIDE + skq * 4]) = h;
            *reinterpret_cast<bf16x4*>(&sAl[row * LDS_STRIDE + skq * 4]) = l;
        }
#pragma unroll
        for (int i = 0; i < 9; ++i) {
            const int row = srow + 32 * i;
            if (row < N_PAD) {
                bf16x4 h, l;
                cvt_hilo(wV[i], &h, &l);
                *reinterpret_cast<bf16x4*>(&sWh[row * LDS_STRIDE + skq * 4]) = h;
                *reinterpret_cast<bf16x4*>(&sWl[row * LDS_STRIDE + skq * 4]) = l;
            }
        }
        __syncthreads();   // LDS visible; no vmem outstanding here (cheap drain)

        // ---- issue next slab's global loads; they fly during the MFMA phase
        load_step(step + 1 < nsteps ? step + 1 : step);

        // ---- compute: 2 row-tiles x 17 col-tiles, hi/lo compensated
        bf16x8 a0h = *reinterpret_cast<const bf16x8*>(&sAh[aoff0]);
        bf16x8 a0l = *reinterpret_cast<const bf16x8*>(&sAl[aoff0]);
        bf16x8 a1h = *reinterpret_cast<const bf16x8*>(&sAh[aoff1]);
        bf16x8 a1l = *reinterpret_cast<const bf16x8*>(&sAl[aoff1]);
#pragma unroll
        for (int ct = 0; ct < 17; ++ct) {
            bf16x8 bh = *reinterpret_cast<const bf16x8*>(
                &sWh[boffb + ct * 16 * LDS_STRIDE]);
            bf16x8 bl = *reinterpret_cast<const bf16x8*>(
                &sWl[boffb + ct * 16 * LDS_STRIDE]);
            acc[0][ct] = __builtin_amdgcn_mfma_f32_16x16x32_bf16(a0h, bh, acc[0][ct], 0, 0, 0);
            acc[0][ct] = __builtin_amdgcn_mfma_f32_16x16x32_bf16(a0l, bh, acc[0][ct], 0, 0, 0);
            acc[0][ct] = __builtin_amdgcn_mfma_f32_16x16x32_bf16(a0h, bl, acc[0][ct], 0, 0, 0);
            acc[1][ct] = __builtin_amdgcn_mfma_f32_16x16x32_bf16(a1h, bh, acc[1][ct], 0, 0, 0);
            acc[1][ct] = __builtin_amdgcn_mfma_f32_16x16x32_bf16(a1l, bh, acc[1][ct], 0, 0, 0);
            acc[1][ct] = __builtin_amdgcn_mfma_f32_16x16x32_bf16(a1h, bl, acc[1][ct], 0, 0, 0);
        }
    }

    // ---- epilogue: C/D layout col = lane&15, row = (lane>>4)*4 + reg [m89]
    const int mbase = mtile * MT + wave * 32;
#pragma unroll
    for (int rt = 0; rt < 2; ++rt) {
#pragma unroll
        for (int ct = 0; ct < 17; ++ct) {
            const int n = ct * 16 + ml;
            if (n < N_REAL) {
#pragma unroll
                for (int r = 0; r < 4; ++r) {
                    const int m = mbase + rt * 16 + q * 4 + r;
                    atomicAdd(acc_ws + (size_t)m * ACC_STRIDE + n,
                              acc[rt][ct][r]);
                }
            }
        }
    }
}

// ---------------------------------------------------------------------------
// Kernel 2: tail MLP. 256 blocks x 256 thr; each wave handles 4 batch rows.
// ---------------------------------------------------------------------------
__global__ __launch_bounds__(256) void nnue_tail(
    const float* __restrict__ acc, const float* __restrict__ b_ft,
    const float* __restrict__ W1, const float* __restrict__ b1,
    const float* __restrict__ W2, const float* __restrict__ b2,
    const float* __restrict__ Wo, const float* __restrict__ bo,
    float* __restrict__ out)
{
    __shared__ float ft[4][512];
    __shared__ float h1buf[4][33];

    const int t    = threadIdx.x;
    const int w    = t >> 6;
    const int lane = t & 63;
    const int half = lane >> 5;
    const int i32  = lane & 31;

    for (int it = 0; it < 4; ++it) {
        const int b = blockIdx.x * 16 + w * 4 + it;

        // stage clamped ft_out = [f1 ; f2] (512) into LDS
#pragma unroll
        for (int ii = 0; ii < 4; ++ii) {
            const int j = ii * 64 + lane;           // 0..255
            float v1 = acc[(size_t)b * ACC_STRIDE + j] + b_ft[j];
            ft[w][j] = fminf(fmaxf(v1, 0.f), 1.f);
            float v2 = acc[(size_t)(b + B_ROWS) * ACC_STRIDE + j] + b_ft[j];
            ft[w][256 + j] = fminf(fmaxf(v2, 0.f), 1.f);
        }
        // psqt: b_ft[256] cancels in the difference
        const float p = 0.5f * (acc[(size_t)b * ACC_STRIDE + 256]
                              - acc[(size_t)(b + B_ROWS) * ACC_STRIDE + 256]);
        __syncthreads();

        // h1: lane = (i32, half); each lane sums 256 of the 512 (vectorized)
        float s = 0.f;
        {
            const f32x4* w1p = reinterpret_cast<const f32x4*>(
                W1 + i32 * 512 + half * 256);
            const f32x4* ftp = reinterpret_cast<const f32x4*>(&ft[w][half * 256]);
#pragma unroll 8
            for (int j = 0; j < 64; ++j) {
                f32x4 a = w1p[j], f = ftp[j];
                s += a.x * f.x + a.y * f.y + a.z * f.z + a.w * f.w;
            }
        }
        s += __shfl_xor(s, 32);
        if (lane < 32)
            h1buf[w][i32] = fminf(fmaxf(s + b1[i32], 0.f), 1.f);
        __syncthreads();

        // h2 + output
        float s2 = 0.f;
        {
            const float* w2p = W2 + i32 * 32 + half * 16;
#pragma unroll
            for (int j = 0; j < 16; ++j) s2 += w2p[j] * h1buf[w][half * 16 + j];
        }
        s2 += __shfl_xor(s2, 32);
        float o = 0.f;
        if (lane < 32) {
            float h2v = fminf(fmaxf(s2 + b2[i32], 0.f), 1.f);
            o = h2v * Wo[i32];
        }
        o += __shfl_xor(o, 16); o += __shfl_xor(o, 8); o += __shfl_xor(o, 4);
        o += __shfl_xor(o, 2);  o += __shfl_xor(o, 1);
        if (lane == 0) out[b] = o + bo[0] + 0.25f * p;
        __syncthreads();
    }
}

// ---------------------------------------------------------------------------
extern "C" void kernel_launch(void* const* d_in, const int* in_sizes, int n_in,
                              void* d_out, int out_size, void* d_ws, size_t ws_size,
                              hipStream_t stream)
{
    const float* feat1 = (const float*)d_in[0];
    const float* feat2 = (const float*)d_in[1];
    const float* Wft   = (const float*)d_in[2];
    const float* b_ft  = (const float*)d_in[3];
    const float* W1    = (const float*)d_in[4];
    const float* b1    = (const float*)d_in[5];
    const float* W2    = (const float*)d_in[6];
    const float* b2    = (const float*)d_in[7];
    const float* Wo    = (const float*)d_in[8];
    const float* bo    = (const float*)d_in[9];
    float* out = (float*)d_out;
    float* acc = (float*)d_ws;   // needs 8192 x 272 x 4 B = 8.9 MB scratch

    hipMemsetAsync(acc, 0, (size_t)M_TOTAL * ACC_STRIDE * sizeof(float), stream);

    ft_gemm<<<dim3(64 * SPLITS), dim3(256), 0, stream>>>(feat1, feat2, Wft, acc);

    nnue_tail<<<dim3(256), dim3(256), 0, stream>>>(acc, b_ft, W1, b1, W2, b2,
                                                   Wo, bo, out);
}

// Round 3
// 1442.137 us; speedup vs baseline: 1.0662x; 1.0662x over previous
//
#include <hip/hip_runtime.h>
#include <hip/hip_bf16.h>

// ---------------------------------------------------------------------------
// NNUE forward:
//   ft = [features1; features2] @ W_ft.T   (8192 x 257)
//   split-K f16 MFMA (W pre-scaled by 2^10 to dodge fp16 denormals),
//   double-buffered LDS with ONE barrier per K-step.
//   tail: bias+clamp, 512->32->32->1 MLP + 0.25 * psqtacc
// ---------------------------------------------------------------------------

#define K_DIM      41600     // FT_IN
#define N_REAL     257
#define N_PAD      272       // 17 * 16
#define ACC_STRIDE 272
#define B_ROWS     4096
#define M_TOTAL    8192
#define MT         128       // M rows per block
#define BK         32        // K per staging step
#define SPLITS     8
#define LDS_STRIDE 40        // 32 + 8 pad halfs (80 B rows: 16B-aligned)
#define WSCALE     1024.0f   // 2^10: keeps W' out of fp16 denormal range
#define WSCALE_INV 0.0009765625f

typedef _Float16 f16x8 __attribute__((ext_vector_type(8)));
typedef _Float16 f16x4 __attribute__((ext_vector_type(4)));
typedef __attribute__((ext_vector_type(4))) float f32x4;

__device__ __forceinline__ f16x4 cvt4(const f32x4 v, const float s) {
    return (f16x4){ (_Float16)(v.x * s), (_Float16)(v.y * s),
                    (_Float16)(v.z * s), (_Float16)(v.w * s) };
}

// ---------------------------------------------------------------------------
// Kernel 1: split-K f16 MFMA GEMM; atomicAdd partials into acc (8192 x 272)
// ---------------------------------------------------------------------------
__global__ __launch_bounds__(256, 2) void ft_gemm(
    const float* __restrict__ feat1, const float* __restrict__ feat2,
    const float* __restrict__ Wft, float* __restrict__ acc_ws)
{
    // double-buffered: 2 x (128 + 272) x 40 halfs = 64,000 B
    __shared__ __align__(16) _Float16 sA[2][MT * LDS_STRIDE];
    __shared__ __align__(16) _Float16 sW[2][N_PAD * LDS_STRIDE];

    const int t    = threadIdx.x;
    const int wave = t >> 6;
    const int lane = t & 63;
    const int q    = lane >> 4;      // quad 0..3
    const int ml   = lane & 15;

    const int s     = blockIdx.x & 7;   // split id (rides XCD round-robin)
    const int mtile = blockIdx.x >> 3;  // 0..63

    // 1300 k-steps = 8*162 + 4: first 4 splits take 163
    const int start  = s * 162 + (s < 4 ? s : 4);
    const int nsteps = 162 + (s < 4 ? 1 : 0);

    const float* Abase = (mtile < 32)
        ? (feat1 + (size_t)mtile * MT * K_DIM)
        : (feat2 + (size_t)(mtile - 32) * MT * K_DIM);

    f32x4 acc[2][17];
#pragma unroll
    for (int rt = 0; rt < 2; ++rt)
#pragma unroll
        for (int ct = 0; ct < 17; ++ct)
            acc[rt][ct] = (f32x4){0.f, 0.f, 0.f, 0.f};

    // fragment element offsets (A-operand: row=lane&15, k=quad*8+j)
    const int aoff0 = (wave * 32 + ml) * LDS_STRIDE + q * 8;
    const int aoff1 = aoff0 + 16 * LDS_STRIDE;
    const int boffb = ml * LDS_STRIDE + q * 8;

    // staging geometry: thread t covers row (t>>3)+32i, k-chunk (t&7)*4
    const int srow = t >> 3;
    const int skq  = t & 7;

    f32x4 aV[4];   // A slab regs
    f32x4 wV[9];   // W slab regs (i=8 only for srow<16, i.e. t<128)

    auto load_step = [&](int step) {
        const int k0 = (start + step) * BK;
        const float* ap = Abase + (size_t)srow * K_DIM + k0 + skq * 4;
#pragma unroll
        for (int i = 0; i < 4; ++i)
            aV[i] = *reinterpret_cast<const f32x4*>(ap + (size_t)(32 * i) * K_DIM);
#pragma unroll
        for (int i = 0; i < 9; ++i) {
            const int row = srow + 32 * i;
            if (row < N_PAD) {
                const int grow = row < N_REAL ? row : (N_REAL - 1);
                wV[i] = *reinterpret_cast<const f32x4*>(
                    Wft + (size_t)grow * K_DIM + k0 + skq * 4);
            }
        }
    };

    auto stage = [&](int buf) {
#pragma unroll
        for (int i = 0; i < 4; ++i) {
            const int row = srow + 32 * i;
            *reinterpret_cast<f16x4*>(&sA[buf][row * LDS_STRIDE + skq * 4]) =
                cvt4(aV[i], 1.0f);
        }
#pragma unroll
        for (int i = 0; i < 9; ++i) {
            const int row = srow + 32 * i;
            if (row < N_PAD)
                *reinterpret_cast<f16x4*>(&sW[buf][row * LDS_STRIDE + skq * 4]) =
                    cvt4(wV[i], WSCALE);
        }
    };

    // prologue: slab 0 -> buf 0
    load_step(0);
    stage(0);
    __syncthreads();

    int p = 0;
#pragma unroll 1
    for (int step = 0; step < nsteps; ++step) {
        // next slab's global loads fly during the MFMA phase
        load_step(step + 1 < nsteps ? step + 1 : step);

        // compute on buf p
        f16x8 a0 = *reinterpret_cast<const f16x8*>(&sA[p][aoff0]);
        f16x8 a1 = *reinterpret_cast<const f16x8*>(&sA[p][aoff1]);
#pragma unroll
        for (int ct = 0; ct < 17; ++ct) {
            f16x8 b = *reinterpret_cast<const f16x8*>(
                &sW[p][boffb + ct * 16 * LDS_STRIDE]);
            acc[0][ct] = __builtin_amdgcn_mfma_f32_16x16x32_f16(a0, b, acc[0][ct], 0, 0, 0);
            acc[1][ct] = __builtin_amdgcn_mfma_f32_16x16x32_f16(a1, b, acc[1][ct], 0, 0, 0);
        }

        // convert + stage next slab into the other buffer (vmcnt wait lands
        // here, ~a full compute phase after the loads were issued)
        stage(p ^ 1);
        __syncthreads();   // ONE barrier per step
        p ^= 1;
    }

    // epilogue: C/D layout col = lane&15, row = (lane>>4)*4 + reg [m89]
    // undo the W pre-scale (exact power of two)
    const int mbase = mtile * MT + wave * 32;
#pragma unroll
    for (int rt = 0; rt < 2; ++rt) {
#pragma unroll
        for (int ct = 0; ct < 17; ++ct) {
            const int n = ct * 16 + ml;
            if (n < N_REAL) {
#pragma unroll
                for (int r = 0; r < 4; ++r) {
                    const int m = mbase + rt * 16 + q * 4 + r;
                    atomicAdd(acc_ws + (size_t)m * ACC_STRIDE + n,
                              acc[rt][ct][r] * WSCALE_INV);
                }
            }
        }
    }
}

// ---------------------------------------------------------------------------
// Kernel 2: tail MLP. 256 blocks x 256 thr; each wave handles 4 batch rows.
// ---------------------------------------------------------------------------
__global__ __launch_bounds__(256) void nnue_tail(
    const float* __restrict__ acc, const float* __restrict__ b_ft,
    const float* __restrict__ W1, const float* __restrict__ b1,
    const float* __restrict__ W2, const float* __restrict__ b2,
    const float* __restrict__ Wo, const float* __restrict__ bo,
    float* __restrict__ out)
{
    __shared__ float ft[4][512];
    __shared__ float h1buf[4][33];

    const int t    = threadIdx.x;
    const int w    = t >> 6;
    const int lane = t & 63;
    const int half = lane >> 5;
    const int i32  = lane & 31;

    for (int it = 0; it < 4; ++it) {
        const int b = blockIdx.x * 16 + w * 4 + it;

        // stage clamped ft_out = [f1 ; f2] (512) into LDS
#pragma unroll
        for (int ii = 0; ii < 4; ++ii) {
            const int j = ii * 64 + lane;           // 0..255
            float v1 = acc[(size_t)b * ACC_STRIDE + j] + b_ft[j];
            ft[w][j] = fminf(fmaxf(v1, 0.f), 1.f);
            float v2 = acc[(size_t)(b + B_ROWS) * ACC_STRIDE + j] + b_ft[j];
            ft[w][256 + j] = fminf(fmaxf(v2, 0.f), 1.f);
        }
        // psqt: b_ft[256] cancels in the difference
        const float p = 0.5f * (acc[(size_t)b * ACC_STRIDE + 256]
                              - acc[(size_t)(b + B_ROWS) * ACC_STRIDE + 256]);
        __syncthreads();

        // h1: lane = (i32, half); each lane sums 256 of the 512 (vectorized)
        float s = 0.f;
        {
            const f32x4* w1p = reinterpret_cast<const f32x4*>(
                W1 + i32 * 512 + half * 256);
            const f32x4* ftp = reinterpret_cast<const f32x4*>(&ft[w][half * 256]);
#pragma unroll 8
            for (int j = 0; j < 64; ++j) {
                f32x4 a = w1p[j], f = ftp[j];
                s += a.x * f.x + a.y * f.y + a.z * f.z + a.w * f.w;
            }
        }
        s += __shfl_xor(s, 32);
        if (lane < 32)
            h1buf[w][i32] = fminf(fmaxf(s + b1[i32], 0.f), 1.f);
        __syncthreads();

        // h2 + output
        float s2 = 0.f;
        {
            const float* w2p = W2 + i32 * 32 + half * 16;
#pragma unroll
            for (int j = 0; j < 16; ++j) s2 += w2p[j] * h1buf[w][half * 16 + j];
        }
        s2 += __shfl_xor(s2, 32);
        float o = 0.f;
        if (lane < 32) {
            float h2v = fminf(fmaxf(s2 + b2[i32], 0.f), 1.f);
            o = h2v * Wo[i32];
        }
        o += __shfl_xor(o, 16); o += __shfl_xor(o, 8); o += __shfl_xor(o, 4);
        o += __shfl_xor(o, 2);  o += __shfl_xor(o, 1);
        if (lane == 0) out[b] = o + bo[0] + 0.25f * p;
        __syncthreads();
    }
}

// ---------------------------------------------------------------------------
extern "C" void kernel_launch(void* const* d_in, const int* in_sizes, int n_in,
                              void* d_out, int out_size, void* d_ws, size_t ws_size,
                              hipStream_t stream)
{
    const float* feat1 = (const float*)d_in[0];
    const float* feat2 = (const float*)d_in[1];
    const float* Wft   = (const float*)d_in[2];
    const float* b_ft  = (const float*)d_in[3];
    const float* W1    = (const float*)d_in[4];
    const float* b1    = (const float*)d_in[5];
    const float* W2    = (const float*)d_in[6];
    const float* b2    = (const float*)d_in[7];
    const float* Wo    = (const float*)d_in[8];
    const float* bo    = (const float*)d_in[9];
    float* out = (float*)d_out;
    float* acc = (float*)d_ws;   // 8192 x 272 x 4 B = 8.9 MB scratch

    hipMemsetAsync(acc, 0, (size_t)M_TOTAL * ACC_STRIDE * sizeof(float), stream);

    ft_gemm<<<dim3(64 * SPLITS), dim3(256), 0, stream>>>(feat1, feat2, Wft, acc);

    nnue_tail<<<dim3(256), dim3(256), 0, stream>>>(acc, b_ft, W1, b1, W2, b2,
                                                   Wo, bo, out);
}